// Round 3
// baseline (648.832 us; speedup 1.0000x reference)
//
#include <hip/hip_runtime.h>
#include <stdint.h>

#define T_TOK 8192
#define K_IN  4096
#define O_OUT 6144

typedef __attribute__((ext_vector_type(4))) float f32x4;
typedef __attribute__((ext_vector_type(8))) int i32x8;
typedef unsigned int uint32;

// ---------- helpers ----------

__device__ inline void load_lds_16(const void* g, void* l) {
    __builtin_amdgcn_global_load_lds(
        (const __attribute__((address_space(1))) unsigned int*)g,
        (__attribute__((address_space(3))) unsigned int*)l, 16, 0, 0);
}

// pack 4 floats -> 4 fp8 e4m3 bytes (RNE, saturating), byte i = input i
__device__ inline int pack4_fp8(float a, float b, float c, float d) {
    int r = __builtin_amdgcn_cvt_pk_fp8_f32(a, b, 0, false);  // bytes 0,1
    r = __builtin_amdgcn_cvt_pk_fp8_f32(c, d, r, true);       // bytes 2,3
    return r;
}

// ---------- kernel 1: per-token dynamic fp8 quantization of x ----------
__global__ __launch_bounds__(256) void quant_x(const float* __restrict__ x,
                                               uint32* __restrict__ xq,
                                               float* __restrict__ xscale) {
    const int t   = blockIdx.x;
    const int tid = threadIdx.x;
    const float4* row4 = (const float4*)(x + (size_t)t * K_IN);

    float4 v[4];
    float amax = 0.f;
#pragma unroll
    for (int j = 0; j < 4; ++j) {
        v[j] = row4[tid + j * 256];
        amax = fmaxf(amax, fmaxf(fmaxf(fabsf(v[j].x), fabsf(v[j].y)),
                                 fmaxf(fabsf(v[j].z), fabsf(v[j].w))));
    }
#pragma unroll
    for (int off = 32; off > 0; off >>= 1)
        amax = fmaxf(amax, __shfl_down(amax, off, 64));
    __shared__ float red[4];
    if ((tid & 63) == 0) red[tid >> 6] = amax;
    __syncthreads();
    amax = fmaxf(fmaxf(red[0], red[1]), fmaxf(red[2], red[3]));

    const float scale = fmaxf(amax, 1e-12f) / 448.0f;
    if (tid == 0) xscale[t] = scale;

    uint32* orow = xq + (size_t)t * (K_IN / 4);
#pragma unroll
    for (int j = 0; j < 4; ++j) {
        // correctly-rounded fp32 division matches the reference's x / x_scale
        float q0 = v[j].x / scale, q1 = v[j].y / scale;
        float q2 = v[j].z / scale, q3 = v[j].w / scale;
        orow[tid + j * 256] = (uint32)pack4_fp8(q0, q1, q2, q3);  // coalesced dword
    }
}

// ---------- kernel 2: fp8 quantization of W (scale applied inside GEMM) ----------
__global__ __launch_bounds__(256) void quant_w(const float* __restrict__ w,
                                               uint32* __restrict__ wq) {
    const size_t u = (size_t)blockIdx.x * 256 + threadIdx.x;  // dword index
    float4 v = ((const float4*)w)[u];
    wq[u] = (uint32)pack4_fp8(v.x, v.y, v.z, v.w);
}

// ---------- kernel 3: fp8 MX GEMM, 256x256x128 tile, 8 waves ----------
// A: [T][K] fp8 bytes, B: [O][K] fp8 bytes.
// C[t][o] = xs[t] * sum_kb s[o/128][kb] * (A.B)_kb   (Horner per K-tile)
//
// Structure (vs the 336us 4-phase lockstep version):
//  * A only in LDS: 4-slot ring (4 x 32 KB), chunk kb+3 staged during body kb.
//    Every prefetch is issued at BODY START and only needed >=1 full body
//    (~2200 cy of MFMA) later, so even __syncthreads' vmcnt(0) drain at body
//    end has full latency cover (~900 cy HBM). ONE barrier per K-tile
//    (was 9): within a body the slot is read-only, waves free-run, and
//    ds_read/L2 latency overlaps MFMA across the 2 waves/SIMD.
//  * B fragments load global->VGPR directly (byte-identical to the old LDS
//    path), double-buffered bA/bB static-named (rule #20), prefetched 1 body
//    ahead. Removes 128 KB/kb of LDS traffic, all B staging, and the B-side
//    bank conflicts. B panel (1 MB/bn) stays L2-resident.
//  * No inline asm anywhere: compiler manages all waitcnts (m97 behavior:
//    fine-grained lgkmcnt between ds_read and MFMA).
__global__ __launch_bounds__(512, 2) void gemm_fp8(const unsigned char* __restrict__ A,
                                                   const unsigned char* __restrict__ B,
                                                   const float* __restrict__ sinv,
                                                   const float* __restrict__ xscale,
                                                   float* __restrict__ C) {
    constexpr int BM = 256, BN = 256, BK = 128;
    constexpr int NKB = K_IN / BK;  // 32 K-tiles, one weight-scale block each
    extern __shared__ unsigned char smem[];  // 128 KB: A ring, slot c -> smem + (c&3)*32768

    const int bn  = blockIdx.x;      // 24 o-tiles (each spans 2 scale blocks)
    const int bm  = blockIdx.y;      // 32 token tiles
    const int tid = threadIdx.x;
    const int lane = tid & 63;
    const int wv   = tid >> 6;
    const int wm   = (wv >> 2) * 128;   // wave M offset in tile
    const int wn   = (wv & 3) * 64;     // wave N offset in tile
    const int G2   = (lane >> 4) * 2;   // k-chunk pair for this lane group

    // ---- A staging: linear LDS dest (gload_lds lane rule), swizzle on the
    //      GLOBAL source chunk index (rule #21). Row r holds chunk j^(r&7) in slot j.
    const int tr = tid >> 3;
    const int kc = (tid & 7) ^ (tr & 7);
    const unsigned char* Ag = A + (size_t)(bm * BM + tr) * K_IN + kc * 16;
    const int ldst = tid * 16;

    // ---- A fragment-read constants (r&7 == lane&7 for all fragment rows)
    const int rA  = lane & 15;
    const int cs0 = ((G2    ) ^ (lane & 7)) * 16;
    const int cs1 = ((G2 + 1) ^ (lane & 7)) * 16;

    // ---- B fragment global base: frag j = row bn*BN+wn+j*16+rA,
    //      bytes kb*128 + G2*16 .. +31 (identical bytes to the old LDS path)
    const unsigned char* Bg = B + (size_t)(bn * BN + wn + rA) * K_IN + G2 * 16;

    const float* srow = sinv + (size_t)(bn * 2 + (wn >> 7)) * NKB;

    union F { i32x8 v; int4 h[2]; };
    f32x4 acc[8][4] = {};
    F bA[4], bB[4];
    float s_prev = srow[0];

// stage A chunk ck into ring slot ck&3 (4 x gload_lds, 64-row strides; &31
// wraps the tail prefetch onto valid memory - those slots are never read)
#define STAGE(ck_) {                                                         \
    unsigned char* d_ = smem + (size_t)((ck_) & 3) * 32768 + ldst;           \
    const unsigned char* g_ = Ag + (size_t)((ck_) & 31) * BK;                \
    load_lds_16(g_,                      d_);                                \
    load_lds_16(g_ + (size_t) 64 * K_IN, d_ +  8192);                        \
    load_lds_16(g_ + (size_t)128 * K_IN, d_ + 16384);                        \
    load_lds_16(g_ + (size_t)192 * K_IN, d_ + 24576); }

// load the 4 B fragments of K-tile ck into regs (8 x global_load_dwordx4)
#define LOADB(dst_, ck_) {                                                   \
    const unsigned char* g_ = Bg + (size_t)((ck_) & 31) * BK;                \
    dst_[0].h[0] = *(const int4*)(g_);                                       \
    dst_[0].h[1] = *(const int4*)(g_ + 16);                                  \
    dst_[1].h[0] = *(const int4*)(g_ + (size_t)16 * K_IN);                   \
    dst_[1].h[1] = *(const int4*)(g_ + (size_t)16 * K_IN + 16);              \
    dst_[2].h[0] = *(const int4*)(g_ + (size_t)32 * K_IN);                   \
    dst_[2].h[1] = *(const int4*)(g_ + (size_t)32 * K_IN + 16);              \
    dst_[3].h[0] = *(const int4*)(g_ + (size_t)48 * K_IN);                   \
    dst_[3].h[1] = *(const int4*)(g_ + (size_t)48 * K_IN + 16); }

#define LDA(d_, i_, pA_) {                                                   \
    const unsigned char* q_ = (pA_) + (wm + (i_) * 16 + rA) * 128;           \
    (d_).h[0] = *(const int4*)(q_ + cs0);                                    \
    (d_).h[1] = *(const int4*)(q_ + cs1); }

#define MFMA(i_, j_, af_, bf_)                                               \
    acc[i_][j_] = __builtin_amdgcn_mfma_scale_f32_16x16x128_f8f6f4(          \
        (af_).v, (bf_).v, acc[i_][j_], 0 /*A=fp8*/, 0 /*B=fp8*/,             \
        0, 0x7f7f7f7f, 0, 0x7f7f7f7f);

// One K-tile: issue next-body prefetches first (B kb+1 -> regs, A kb+3 ->
// ring slot), then the 8x4 MFMA quadrant sweep on the landed slot kb&3.
// __syncthreads at body end is the single barrier: drains this body's
// prefetch DMA (full-body MFMA cover) and publishes slot (kb+1)&3.
#define KB_BODY(kb_, bcur_, bnxt_) {                                         \
    const unsigned char* pA = smem + (size_t)((kb_) & 3) * 32768;            \
    const float s_cur = srow[kb_];                                           \
    const float rr = s_prev / s_cur;   /* exactly 1.0 at kb==0 */            \
    s_prev = s_cur;                                                          \
    LOADB(bnxt_, (kb_) + 1);                                                 \
    STAGE((kb_) + 3);                                                        \
    __builtin_amdgcn_s_setprio(1);                                           \
    _Pragma("unroll")                                                        \
    for (int i = 0; i < 8; ++i) {                                            \
        F af; LDA(af, i, pA);                                                \
        acc[i][0] *= rr; acc[i][1] *= rr; acc[i][2] *= rr; acc[i][3] *= rr;  \
        MFMA(i, 0, af, bcur_[0]); MFMA(i, 1, af, bcur_[1]);                  \
        MFMA(i, 2, af, bcur_[2]); MFMA(i, 3, af, bcur_[3]);                  \
    }                                                                        \
    __builtin_amdgcn_s_setprio(0);                                           \
    __syncthreads(); }

    // ---- prologue: B(0) + A chunks 0..2 staged; __syncthreads drains all.
    LOADB(bA, 0);
    STAGE(0); STAGE(1); STAGE(2);
    __syncthreads();

    for (int kb = 0; kb < NKB; kb += 2) {
        KB_BODY(kb,     bA, bB);
        KB_BODY(kb + 1, bB, bA);
    }

    // epilogue: D col=lane&15, row=(lane>>4)*4+reg; final scale = s_last * xs[token]
#pragma unroll
    for (int i = 0; i < 8; ++i) {
#pragma unroll
        for (int r = 0; r < 4; ++r) {
            const int m_g = bm * BM + wm + i * 16 + (lane >> 4) * 4 + r;
            const float f = xscale[m_g] * s_prev;
            float* crow = C + (size_t)m_g * O_OUT + bn * BN + wn;
#pragma unroll
            for (int j = 0; j < 4; ++j)
                crow[j * 16 + (lane & 15)] = acc[i][j][r] * f;
        }
    }
#undef STAGE
#undef LOADB
#undef LDA
#undef MFMA
#undef KB_BODY
}

// ---------- launch ----------
extern "C" void kernel_launch(void* const* d_in, const int* in_sizes, int n_in,
                              void* d_out, int out_size, void* d_ws, size_t ws_size,
                              hipStream_t stream) {
    const float* x    = (const float*)d_in[0];
    const float* w    = (const float*)d_in[1];
    const float* sinv = (const float*)d_in[2];
    float* out = (float*)d_out;

    char* ws = (char*)d_ws;
    uint32* xq = (uint32*)ws;                                   // 32 MB (fp8 bytes)
    uint32* wq = (uint32*)(ws + (size_t)T_TOK * K_IN);          // 24 MB
    float* xscale = (float*)(ws + (size_t)T_TOK * K_IN
                                + (size_t)O_OUT * K_IN);        // 32 KB

    quant_x<<<T_TOK, 256, 0, stream>>>(x, xq, xscale);
    quant_w<<<(O_OUT * K_IN) / (4 * 256), 256, 0, stream>>>(w, wq);
    dim3 grid(O_OUT / 256, T_TOK / 256);   // (24, 32)
    gemm_fp8<<<grid, 512, 131072 /*dynamic LDS: 4-slot A ring*/, stream>>>(
        (const unsigned char*)xq, (const unsigned char*)wq, sinv, xscale, out);
}